// Round 4
// baseline (269.564 us; speedup 1.0000x reference)
//
#include <hip/hip_runtime.h>
#include <math.h>

#define DIM 8388608
#define NBLK_RED 1024
#define EPS_F 1e-10f

typedef _Float16 h2 __attribute__((ext_vector_type(2)));
typedef _Float16 h8 __attribute__((ext_vector_type(8)));
typedef __fp16 g2 __attribute__((ext_vector_type(2)));   // __builtin_amdgcn_cvt_pkrtz return type
typedef float f32x16 __attribute__((ext_vector_type(16)));

// ws layout (floats):
// [0 .. 4096)    per-block reduction partials: float4 per block {sum g^2, sum d^2, sum g*d, max|g|}
// [4096..4101)   s0, s1, s2, s3 (coeff_k * inv_norm), isq = 1/sqrt(1+it)
// [4104..5896)   MFMA A-fragment weight table: uint4[7 frags][64 lanes]
//                frag f, lane l: 8 f16 = W_aug[row = l&31][k = k0(f) + (l>>5)*8 + j], j=0..7
//                W_aug = [W | bias-col | 0-pad] (bias as constant-1.0 input channel)
//                f0: L0 (20x4+bias, K=16); f1,2: L1 (20x20+bias, k0=0/16);
//                f3,4: L2; f5,6: L3 (1x20+bias)
#define WS_SCAL 4096
#define WS_FRG  4104

static __device__ __forceinline__ unsigned h2_bits(h2 v) {
    union { h2 h; unsigned u; } c; c.h = v; return c.u;
}
static __device__ __forceinline__ h8 h8_from4(unsigned a, unsigned b, unsigned c, unsigned d) {
    union { unsigned u[4]; h8 h; } x; x.u[0] = a; x.u[1] = b; x.u[2] = c; x.u[3] = d; return x.h;
}
// v_cvt_pkrtz_f16_f32 with a bit-cast to our _Float16 vector type
static __device__ __forceinline__ h2 pkrtz(float a, float b) {
    union { g2 g; h2 h; } c; c.g = __builtin_amdgcn_cvt_pkrtz(a, b); return c.h;
}
static __device__ __forceinline__ h2 relu_pk(h2 v) {
    const h2 z = {(_Float16)0.f, (_Float16)0.f};
    return __builtin_elementwise_max(v, z);
}
static __device__ __forceinline__ unsigned pkrelu(float a, float b) {
    return h2_bits(relu_pk(pkrtz(a, b)));
}
// v_permlane32_swap_b32 a, b: exchanges a's values in lanes 32-63 with b's
// values in lanes 0-31 (both registers modified). Inline asm to sidestep
// builtin-signature variance.
static __device__ __forceinline__ void plswap(unsigned &a, unsigned &b) {
    asm volatile("v_permlane32_swap_b32 %0, %1" : "+v"(a), "+v"(b));
}
#define MFMA16(a, b, c) __builtin_amdgcn_mfma_f32_32x32x16_f16((a), (b), (c), 0, 0, 0)

// Layer transition: acc (32x32x16 D layout) -> two K=16 B fragments of the
// next layer (K=32 padded: k 0-19 data, k=20 bias-1.0 channel, k>20 zero).
// D row (r&3)+8*(r>>2)+4*(lane>>5): regs0-3=rows0-3(lo)/4-7(up), regs4-7=
// rows8-11/12-15, regs8-11=rows16-19/20-23(zero). B k = 8*(lane>>5)+j.
// Two permlane32_swaps produce words {0,2} and {1,3} of b0 simultaneously;
// b1 needs no swap (its upper-lane rows are structurally zero).
static __device__ __forceinline__ void transition(const f32x16 &a, bool low, h8 &b0, h8 &b1) {
    unsigned p0 = pkrelu(a[0], a[1]);    // rows {0,1} lo / {4,5} up
    unsigned p1 = pkrelu(a[2], a[3]);    // rows {2,3} / {6,7}
    unsigned p2 = pkrelu(a[4], a[5]);    // rows {8,9} / {12,13}
    unsigned p3 = pkrelu(a[6], a[7]);    // rows {10,11} / {14,15}
    unsigned p4 = pkrelu(a[8], a[9]);    // rows {16,17} / {20,21}=0
    unsigned p5 = pkrelu(a[10], a[11]);  // rows {18,19} / {22,23}=0
    plswap(p0, p2);   // p0: rows{0,1}/{8,9}   p2: rows{4,5}/{12,13}
    plswap(p1, p3);   // p1: rows{2,3}/{10,11} p3: rows{6,7}/{14,15}
    b0 = h8_from4(p0, p1, p2, p3);
    b1 = h8_from4(p4, p5, low ? 0x00003C00u : 0u, 0u);  // k20 = bias 1.0 (lo half)
}

__global__ __launch_bounds__(256) void reduce_k(const float4* __restrict__ g4,
                                                const float4* __restrict__ a4,
                                                const float4* __restrict__ b4,
                                                float4* __restrict__ part4) {
    const int N4 = DIM / 4;
    int tid = blockIdx.x * blockDim.x + threadIdx.x;
    int stride = gridDim.x * blockDim.x;
    float ssg = 0.f, ssd = 0.f, sgd = 0.f, mx = 0.f;
    for (int i = tid; i < N4; i += stride) {
        float4 gv = g4[i], av = a4[i], bv = b4[i];
        float d0 = bv.x - av.x, d1 = bv.y - av.y, d2 = bv.z - av.z, d3 = bv.w - av.w;
        ssg = fmaf(gv.x, gv.x, ssg); ssg = fmaf(gv.y, gv.y, ssg);
        ssg = fmaf(gv.z, gv.z, ssg); ssg = fmaf(gv.w, gv.w, ssg);
        ssd = fmaf(d0, d0, ssd); ssd = fmaf(d1, d1, ssd);
        ssd = fmaf(d2, d2, ssd); ssd = fmaf(d3, d3, ssd);
        sgd = fmaf(gv.x, d0, sgd); sgd = fmaf(gv.y, d1, sgd);
        sgd = fmaf(gv.z, d2, sgd); sgd = fmaf(gv.w, d3, sgd);
        mx = fmaxf(mx, fabsf(gv.x)); mx = fmaxf(mx, fabsf(gv.y));
        mx = fmaxf(mx, fabsf(gv.z)); mx = fmaxf(mx, fabsf(gv.w));
    }
    #pragma unroll
    for (int off = 32; off > 0; off >>= 1) {
        ssg += __shfl_down(ssg, off);
        ssd += __shfl_down(ssd, off);
        sgd += __shfl_down(sgd, off);
        mx = fmaxf(mx, __shfl_down(mx, off));
    }
    __shared__ float sm[4][4];
    int lane = threadIdx.x & 63, wid = threadIdx.x >> 6;
    if (lane == 0) { sm[wid][0] = ssg; sm[wid][1] = ssd; sm[wid][2] = sgd; sm[wid][3] = mx; }
    __syncthreads();
    if (threadIdx.x == 0) {
        float t0 = 0.f, t1 = 0.f, t2 = 0.f, t3 = 0.f;
        #pragma unroll
        for (int w = 0; w < 4; ++w) {
            t0 += sm[w][0]; t1 += sm[w][1]; t2 += sm[w][2]; t3 = fmaxf(t3, sm[w][3]);
        }
        part4[blockIdx.x] = make_float4(t0, t1, t2, t3);
    }
}

// Augmented weight fetch: [W | bias-at-k==cols | zeros]
static __device__ __forceinline__ float waug(const float* __restrict__ W,
                                             const float* __restrict__ B,
                                             int rows, int cols, int i, int k) {
    if (i >= rows) return 0.f;
    if (k < cols)  return W[i * cols + k];
    if (k == cols) return B[i];
    return 0.f;
}
static __device__ __forceinline__ unsigned packw(const float* __restrict__ W,
                                                 const float* __restrict__ B,
                                                 int rows, int cols, int i, int k) {
    h2 v = {(_Float16)waug(W, B, rows, cols, i, k),
            (_Float16)waug(W, B, rows, cols, i, k + 1)};
    return h2_bits(v);
}
// 8 consecutive k per lane (contiguous-K layout of the gfx950 2xK shapes)
static __device__ __forceinline__ uint4 mkfrag16(const float* __restrict__ W,
                                                 const float* __restrict__ B,
                                                 int rows, int cols, int i, int kb) {
    uint4 r;
    r.x = packw(W, B, rows, cols, i, kb + 0);
    r.y = packw(W, B, rows, cols, i, kb + 2);
    r.z = packw(W, B, rows, cols, i, kb + 4);
    r.w = packw(W, B, rows, cols, i, kb + 6);
    return r;
}

__global__ __launch_bounds__(64) void mlp_k(float* __restrict__ wsf,
                                            const float* __restrict__ loss_cur,
                                            const float* __restrict__ loss_old,
                                            const int* __restrict__ iter,
                                            const float* __restrict__ lw0, const float* __restrict__ lb0,
                                            const float* __restrict__ lw1, const float* __restrict__ lb1,
                                            const float* __restrict__ lw2, const float* __restrict__ lb2,
                                            const float* __restrict__ lw3, const float* __restrict__ lb3,
                                            const float* __restrict__ cw0, const float* __restrict__ cb0,
                                            const float* __restrict__ cw1, const float* __restrict__ cb1,
                                            const float* __restrict__ cw2, const float* __restrict__ cb2,
                                            const float* __restrict__ cw3, const float* __restrict__ cb3) {
    int t = threadIdx.x;

    // --- pack conv weights into per-lane 32x32x16 MFMA A-fragments ---
    uint4* frg = (uint4*)(wsf + WS_FRG);
    int i = t & 31, kb = (t >> 5) * 8;
    frg[0 * 64 + t] = mkfrag16(cw0, cb0, 20, 4,  i, kb);
    frg[1 * 64 + t] = mkfrag16(cw1, cb1, 20, 20, i, kb);
    frg[2 * 64 + t] = mkfrag16(cw1, cb1, 20, 20, i, 16 + kb);
    frg[3 * 64 + t] = mkfrag16(cw2, cb2, 20, 20, i, kb);
    frg[4 * 64 + t] = mkfrag16(cw2, cb2, 20, 20, i, 16 + kb);
    frg[5 * 64 + t] = mkfrag16(cw3, cb3, 1,  20, i, kb);
    frg[6 * 64 + t] = mkfrag16(cw3, cb3, 1,  20, i, 16 + kb);

    // --- final reduction over per-block partials ---
    const float4* part4 = (const float4*)wsf;
    float ssg = 0.f, ssd = 0.f, sgd = 0.f, mx = 0.f;
    for (int b = t; b < NBLK_RED; b += 64) {
        float4 p = part4[b];
        ssg += p.x; ssd += p.y; sgd += p.z; mx = fmaxf(mx, p.w);
    }
    #pragma unroll
    for (int off = 32; off > 0; off >>= 1) {
        ssg += __shfl_down(ssg, off);
        ssd += __shfl_down(ssd, off);
        sgd += __shfl_down(sgd, off);
        mx = fmaxf(mx, __shfl_down(mx, off));
    }
    __shared__ float red[4];
    if (t == 0) { red[0] = ssg; red[1] = ssd; red[2] = sgd; red[3] = mx; }
    __syncthreads();

    __shared__ float buf[32];
    __shared__ float nxt[32];
    float gn = sqrtf(red[0]);
    float dn = sqrtf(red[1]);
    float inv_gn = (gn > EPS_F) ? 1.f / gn : 1.f;
    float inv_dn = (dn > EPS_F) ? 1.f / dn : 1.f;
    float it = (float)iter[0];
    if (t < 6) {
        float f = 0.f;
        if (t == 0) f = log1pf(gn);
        else if (t == 1) f = log1pf(dn);
        else if (t == 2) f = red[2] * inv_gn * inv_dn;
        else if (t == 3) f = red[3] * inv_gn;
        else if (t == 4) f = it;
        else f = logf(loss_cur[0]) - logf(loss_old[0]);
        buf[t] = f;
    }
    __syncthreads();
    float acc;
    if (t < 30) {
        acc = lb0[t];
        #pragma unroll
        for (int c = 0; c < 6; ++c) acc = fmaf(lw0[t * 6 + c], buf[c], acc);
        nxt[t] = fmaxf(acc, 0.f);
    }
    __syncthreads();
    if (t < 20) {
        acc = lb1[t];
        #pragma unroll
        for (int c = 0; c < 30; ++c) acc = fmaf(lw1[t * 30 + c], nxt[c], acc);
        buf[t] = fmaxf(acc, 0.f);
    }
    __syncthreads();
    if (t < 10) {
        acc = lb2[t];
        #pragma unroll
        for (int c = 0; c < 20; ++c) acc = fmaf(lw2[t * 20 + c], buf[c], acc);
        nxt[t] = fmaxf(acc, 0.f);
    }
    __syncthreads();
    if (t < 4) {
        acc = lb3[t];
        #pragma unroll
        for (int c = 0; c < 10; ++c) acc = fmaf(lw3[t * 10 + c], nxt[c], acc);
        float s = ((t & 1) == 0) ? acc * inv_gn : acc * inv_dn;  // t=0,2 g-path; t=1,3 d-path
        wsf[WS_SCAL + t] = s;
    }
    if (t == 0) wsf[WS_SCAL + 4] = rsqrtf(1.f + it);
}

// MFMA conv stack: each wave handles 256 elements (8 tiles of 32 columns).
// 32x32x16 chain: 7 MFMAs/tile; layer transitions via 2 permlane32_swaps.
__global__ __launch_bounds__(256) void apply_k(const float4* __restrict__ g4,
                                               const float4* __restrict__ a4,
                                               const float4* __restrict__ b4,
                                               const float4* __restrict__ gp4,
                                               const float4* __restrict__ ex4,
                                               const float* __restrict__ wsf,
                                               float4* __restrict__ out4) {
    __shared__ uint2 xs[4][256];                    // per-elem packed x channels (4 f16)
    __shared__ __align__(16) float os[4][256];      // per-elem conv output (f32)

    const int lane = threadIdx.x & 63;
    const int wv   = threadIdx.x >> 6;
    const bool low = lane < 32;

    const float s0 = wsf[WS_SCAL + 0], s1 = wsf[WS_SCAL + 1];
    const float s2 = wsf[WS_SCAL + 2], s3 = wsf[WS_SCAL + 3];
    const float isq = wsf[WS_SCAL + 4];

    // weight A-fragments (pre-packed by mlp_k), 16B/lane coalesced
    const uint4* __restrict__ frg = (const uint4*)(wsf + WS_FRG);
    h8 wf[7];
    #pragma unroll
    for (int f = 0; f < 7; ++f) {
        uint4 u = frg[f * 64 + lane];
        wf[f] = h8_from4(u.x, u.y, u.z, u.w);
    }

    const int i4 = blockIdx.x * 256 + threadIdx.x;  // this thread's float4 slot
    float4 gv = g4[i4], av = a4[i4], bv = b4[i4], pv = gp4[i4], ev = ex4[i4];
    float GG[4] = {gv.x, gv.y, gv.z, gv.w};
    float PP[4] = {pv.x, pv.y, pv.z, pv.w};
    float EE[4] = {ev.x, ev.y, ev.z, ev.w};
    float DE[4] = {bv.x - av.x, bv.y - av.y, bv.z - av.z, bv.w - av.w};

    // stage x channels to LDS: 4 f16 per element {x0,x1,x2,x3}
    #pragma unroll
    for (int e = 0; e < 4; ++e) {
        float x0 = s0 * PP[e] * GG[e];
        float x1 = s1 * EE[e] * DE[e];
        float x2 = s2 * GG[e];
        float x3 = s3 * DE[e];
        h2 lo = pkrtz(x0, x1);
        h2 hi = pkrtz(x2, x3);
        xs[wv][(lane << 2) + e] = make_uint2(h2_bits(lo), h2_bits(hi));
    }
    __syncthreads();

    f32x16 Z;
    #pragma unroll
    for (int k = 0; k < 16; ++k) Z[k] = 0.f;

    #pragma unroll
    for (int tl = 0; tl < 8; ++tl) {
        uint2 xv = xs[wv][(tl << 5) + (lane & 31)];
        // L0 B (K=16): low half k0-3 = x data, k4 = bias 1.0; upper half zero
        h8 b0 = h8_from4(low ? xv.x : 0u, low ? xv.y : 0u, low ? 0x00003C00u : 0u, 0u);
        f32x16 a0 = MFMA16(wf[0], b0, Z);

        h8 c0, c1;
        transition(a0, low, c0, c1);
        f32x16 a1 = MFMA16(wf[1], c0, Z);
        a1 = MFMA16(wf[2], c1, a1);

        transition(a1, low, c0, c1);
        f32x16 a2 = MFMA16(wf[3], c0, Z);
        a2 = MFMA16(wf[4], c1, a2);

        transition(a2, low, c0, c1);
        f32x16 a3 = MFMA16(wf[5], c0, Z);
        a3 = MFMA16(wf[6], c1, a3);

        // direction for this tile's 32 columns lives in reg0 of lanes 0-31
        if (low) os[wv][(tl << 5) + lane] = a3[0];
    }
    __syncthreads();

    const float4 ov = *reinterpret_cast<const float4*>(&os[wv][lane << 2]);
    float4 outv;
    outv.x = fmaf(ov.x, isq, bv.x);
    outv.y = fmaf(ov.y, isq, bv.y);
    outv.z = fmaf(ov.z, isq, bv.z);
    outv.w = fmaf(ov.w, isq, bv.w);
    out4[i4] = outv;
}

extern "C" void kernel_launch(void* const* d_in, const int* in_sizes, int n_in,
                              void* d_out, int out_size, void* d_ws, size_t ws_size,
                              hipStream_t stream) {
    const float* grad    = (const float*)d_in[0];
    const float* state0  = (const float*)d_in[1];
    const float* state1  = (const float*)d_in[2];
    const float* losscur = (const float*)d_in[3];
    const float* lossold = (const float*)d_in[4];
    const int*   iter    = (const int*)d_in[5];
    const float* gparam  = (const float*)d_in[6];
    const float* extrap  = (const float*)d_in[7];
    const float* cw0 = (const float*)d_in[8];  const float* cb0 = (const float*)d_in[9];
    const float* cw1 = (const float*)d_in[10]; const float* cb1 = (const float*)d_in[11];
    const float* cw2 = (const float*)d_in[12]; const float* cb2 = (const float*)d_in[13];
    const float* cw3 = (const float*)d_in[14]; const float* cb3 = (const float*)d_in[15];
    const float* lw0 = (const float*)d_in[16]; const float* lb0 = (const float*)d_in[17];
    const float* lw1 = (const float*)d_in[18]; const float* lb1 = (const float*)d_in[19];
    const float* lw2 = (const float*)d_in[20]; const float* lb2 = (const float*)d_in[21];
    const float* lw3 = (const float*)d_in[22]; const float* lb3 = (const float*)d_in[23];

    float* wsf = (float*)d_ws;
    float* out = (float*)d_out;

    reduce_k<<<NBLK_RED, 256, 0, stream>>>((const float4*)grad, (const float4*)state0,
                                           (const float4*)state1, (float4*)wsf);

    mlp_k<<<1, 64, 0, stream>>>(wsf, losscur, lossold, iter,
                                lw0, lb0, lw1, lb1, lw2, lb2, lw3, lb3,
                                cw0, cb0, cw1, cb1, cw2, cb2, cw3, cb3);

    apply_k<<<DIM / 1024, 256, 0, stream>>>((const float4*)grad, (const float4*)state0,
                                            (const float4*)state1, (const float4*)gparam,
                                            (const float4*)extrap,
                                            wsf, (float4*)out);
}

// Round 6
// 258.459 us; speedup vs baseline: 1.0430x; 1.0430x over previous
//
#include <hip/hip_runtime.h>
#include <math.h>

#define DIM 8388608
#define NBLK_RED 1024
#define EPS_F 1e-10f

typedef _Float16 h2 __attribute__((ext_vector_type(2)));
typedef __fp16 g2 __attribute__((ext_vector_type(2)));   // __builtin_amdgcn_cvt_pkrtz return type
typedef int i32x4 __attribute__((ext_vector_type(4)));
typedef float f32x16 __attribute__((ext_vector_type(16)));

// ws layout (floats):
// [0 .. 4096)    per-block reduction partials: float4 per block {sum g^2, sum d^2, sum g*d, max|g|}
// [4096..4101)   s0, s1, s2, s3 (coeff_k * inv_norm), isq = 1/sqrt(1+it)
// [4104..5896)   MFMA A-fragment weight table: uint4[7 frags][64 lanes]
//                frag f, lane l: 8 f16 = W_aug[row = l&31][k = k0(f) + (l>>5)*8 + j], j=0..7
//                W_aug = [W | bias-col | 0-pad] (bias as constant-1.0 input channel)
//                f0: L0 (20x4+bias, K=16); f1,2: L1 (20x20+bias, k0=0/16);
//                f3,4: L2; f5,6: L3 (1x20+bias)
#define WS_SCAL 4096
#define WS_FRG  4104

static __device__ __forceinline__ unsigned h2_bits(h2 v) {
    union { h2 h; unsigned u; } c; c.h = v; return c.u;
}
// v_cvt_pkrtz_f16_f32 with a bit-cast to our _Float16 vector type
static __device__ __forceinline__ h2 pkrtz(float a, float b) {
    union { g2 g; h2 h; } c; c.g = __builtin_amdgcn_cvt_pkrtz(a, b); return c.h;
}
static __device__ __forceinline__ h2 relu_pk(h2 v) {
    const h2 z = {(_Float16)0.f, (_Float16)0.f};
    return __builtin_elementwise_max(v, z);
}
static __device__ __forceinline__ unsigned pkrelu(float a, float b) {
    return h2_bits(relu_pk(pkrtz(a, b)));
}
// v_permlane32_swap_b32 a, b: exchanges a's values in lanes 32-63 with b's
// values in lanes 0-31 (both registers modified).
static __device__ __forceinline__ void plswap(unsigned &a, unsigned &b) {
    asm volatile("v_permlane32_swap_b32 %0, %1" : "+v"(a), "+v"(b));
}

// Raw-asm MFMA (VGPR-form, out-of-place D). CDNA has NO hardware interlock
// for the matrix pipe's register hazards; the compiler inserts s_nops for
// intrinsics but cannot see inside asm blobs (R5's NaN). So the wait states
// live INSIDE the blob, inseparable from the MFMA:
//  - lead s_nop 2: covers VALU-write -> MFMA-read SrcA/B/C (~2-3 states)
//  - mfma_pad trail s_nop 7 x3 (24 cyc): covers MFMA DstD -> VALU/mem read
//    (<=22 worst case for 16-pass). Stalls are wave-private: other waves
//    fill the SIMD, unlike R4's real v_accvgpr/mov instructions.
//  - mfma_chain (D consumed only as next MFMA's SrcC = forwarding path,
//    0 wait states): no trailing nops.
static __device__ __forceinline__ f32x16 mfma_pad(i32x4 a, i32x4 b, f32x16 c) {
    f32x16 d;
    asm("s_nop 2\n\t"
        "v_mfma_f32_32x32x16_f16 %0, %1, %2, %3\n\t"
        "s_nop 7\n\t"
        "s_nop 7\n\t"
        "s_nop 7"
        : "=&v"(d)
        : "v"(a), "v"(b), "v"(c));
    return d;
}
static __device__ __forceinline__ f32x16 mfma_chain(i32x4 a, i32x4 b, f32x16 c) {
    f32x16 d;
    asm("s_nop 2\n\t"
        "v_mfma_f32_32x32x16_f16 %0, %1, %2, %3"
        : "=&v"(d)
        : "v"(a), "v"(b), "v"(c));
    return d;
}

// Layer transition: acc (32x32x16 D layout) -> two K=16 B fragments of the
// next layer (K=32 padded: k 0-19 data, k=20 bias-1.0 channel, k>20 zero).
// D row (r&3)+8*(r>>2)+4*(lane>>5): regs0-3=rows0-3(lo)/4-7(up), regs4-7=
// rows8-11/12-15, regs8-11=rows16-19/20-23(zero). B k = 8*(lane>>5)+j.
// Two permlane32_swaps produce words {0,2} and {1,3} of b0 simultaneously.
// b1 word2 = {1.0,0}: lo lanes hit k20 (bias channel), hi lanes hit k28
// whose weight column is zero -> uniform constant, no cndmask. b1 word3
// hits zero weight columns on both halves -> any value.
static __device__ __forceinline__ void transition(const f32x16 &a, i32x4 &b0, i32x4 &b1) {
    unsigned p0 = pkrelu(a[0], a[1]);    // rows {0,1} lo / {4,5} up
    unsigned p1 = pkrelu(a[2], a[3]);    // rows {2,3} / {6,7}
    unsigned p2 = pkrelu(a[4], a[5]);    // rows {8,9} / {12,13}
    unsigned p3 = pkrelu(a[6], a[7]);    // rows {10,11} / {14,15}
    unsigned p4 = pkrelu(a[8], a[9]);    // rows {16,17} / {20,21}=0
    unsigned p5 = pkrelu(a[10], a[11]);  // rows {18,19} / {22,23}=0
    plswap(p0, p2);   // p0: rows{0,1}/{8,9}   p2: rows{4,5}/{12,13}
    plswap(p1, p3);   // p1: rows{2,3}/{10,11} p3: rows{6,7}/{14,15}
    b0 = (i32x4){(int)p0, (int)p1, (int)p2, (int)p3};
    b1 = (i32x4){(int)p4, (int)p5, 0x00003C00, 0};
}

__global__ __launch_bounds__(256) void reduce_k(const float4* __restrict__ g4,
                                                const float4* __restrict__ a4,
                                                const float4* __restrict__ b4,
                                                float4* __restrict__ part4) {
    const int N4 = DIM / 4;
    int tid = blockIdx.x * blockDim.x + threadIdx.x;
    int stride = gridDim.x * blockDim.x;
    float ssg = 0.f, ssd = 0.f, sgd = 0.f, mx = 0.f;
    for (int i = tid; i < N4; i += stride) {
        float4 gv = g4[i], av = a4[i], bv = b4[i];
        float d0 = bv.x - av.x, d1 = bv.y - av.y, d2 = bv.z - av.z, d3 = bv.w - av.w;
        ssg = fmaf(gv.x, gv.x, ssg); ssg = fmaf(gv.y, gv.y, ssg);
        ssg = fmaf(gv.z, gv.z, ssg); ssg = fmaf(gv.w, gv.w, ssg);
        ssd = fmaf(d0, d0, ssd); ssd = fmaf(d1, d1, ssd);
        ssd = fmaf(d2, d2, ssd); ssd = fmaf(d3, d3, ssd);
        sgd = fmaf(gv.x, d0, sgd); sgd = fmaf(gv.y, d1, sgd);
        sgd = fmaf(gv.z, d2, sgd); sgd = fmaf(gv.w, d3, sgd);
        mx = fmaxf(mx, fabsf(gv.x)); mx = fmaxf(mx, fabsf(gv.y));
        mx = fmaxf(mx, fabsf(gv.z)); mx = fmaxf(mx, fabsf(gv.w));
    }
    #pragma unroll
    for (int off = 32; off > 0; off >>= 1) {
        ssg += __shfl_down(ssg, off);
        ssd += __shfl_down(ssd, off);
        sgd += __shfl_down(sgd, off);
        mx = fmaxf(mx, __shfl_down(mx, off));
    }
    __shared__ float sm[4][4];
    int lane = threadIdx.x & 63, wid = threadIdx.x >> 6;
    if (lane == 0) { sm[wid][0] = ssg; sm[wid][1] = ssd; sm[wid][2] = sgd; sm[wid][3] = mx; }
    __syncthreads();
    if (threadIdx.x == 0) {
        float t0 = 0.f, t1 = 0.f, t2 = 0.f, t3 = 0.f;
        #pragma unroll
        for (int w = 0; w < 4; ++w) {
            t0 += sm[w][0]; t1 += sm[w][1]; t2 += sm[w][2]; t3 = fmaxf(t3, sm[w][3]);
        }
        part4[blockIdx.x] = make_float4(t0, t1, t2, t3);
    }
}

// Augmented weight fetch: [W | bias-at-k==cols | zeros]
static __device__ __forceinline__ float waug(const float* __restrict__ W,
                                             const float* __restrict__ B,
                                             int rows, int cols, int i, int k) {
    if (i >= rows) return 0.f;
    if (k < cols)  return W[i * cols + k];
    if (k == cols) return B[i];
    return 0.f;
}
static __device__ __forceinline__ unsigned packw(const float* __restrict__ W,
                                                 const float* __restrict__ B,
                                                 int rows, int cols, int i, int k) {
    h2 v = {(_Float16)waug(W, B, rows, cols, i, k),
            (_Float16)waug(W, B, rows, cols, i, k + 1)};
    return h2_bits(v);
}
// 8 consecutive k per lane (contiguous-K layout of the gfx950 2xK shapes)
static __device__ __forceinline__ uint4 mkfrag16(const float* __restrict__ W,
                                                 const float* __restrict__ B,
                                                 int rows, int cols, int i, int kb) {
    uint4 r;
    r.x = packw(W, B, rows, cols, i, kb + 0);
    r.y = packw(W, B, rows, cols, i, kb + 2);
    r.z = packw(W, B, rows, cols, i, kb + 4);
    r.w = packw(W, B, rows, cols, i, kb + 6);
    return r;
}

__global__ __launch_bounds__(64) void mlp_k(float* __restrict__ wsf,
                                            const float* __restrict__ loss_cur,
                                            const float* __restrict__ loss_old,
                                            const int* __restrict__ iter,
                                            const float* __restrict__ lw0, const float* __restrict__ lb0,
                                            const float* __restrict__ lw1, const float* __restrict__ lb1,
                                            const float* __restrict__ lw2, const float* __restrict__ lb2,
                                            const float* __restrict__ lw3, const float* __restrict__ lb3,
                                            const float* __restrict__ cw0, const float* __restrict__ cb0,
                                            const float* __restrict__ cw1, const float* __restrict__ cb1,
                                            const float* __restrict__ cw2, const float* __restrict__ cb2,
                                            const float* __restrict__ cw3, const float* __restrict__ cb3) {
    int t = threadIdx.x;

    // --- pack conv weights into per-lane 32x32x16 MFMA A-fragments ---
    uint4* frg = (uint4*)(wsf + WS_FRG);
    int i = t & 31, kb = (t >> 5) * 8;
    frg[0 * 64 + t] = mkfrag16(cw0, cb0, 20, 4,  i, kb);
    frg[1 * 64 + t] = mkfrag16(cw1, cb1, 20, 20, i, kb);
    frg[2 * 64 + t] = mkfrag16(cw1, cb1, 20, 20, i, 16 + kb);
    frg[3 * 64 + t] = mkfrag16(cw2, cb2, 20, 20, i, kb);
    frg[4 * 64 + t] = mkfrag16(cw2, cb2, 20, 20, i, 16 + kb);
    frg[5 * 64 + t] = mkfrag16(cw3, cb3, 1,  20, i, kb);
    frg[6 * 64 + t] = mkfrag16(cw3, cb3, 1,  20, i, 16 + kb);

    // --- final reduction over per-block partials ---
    const float4* part4 = (const float4*)wsf;
    float ssg = 0.f, ssd = 0.f, sgd = 0.f, mx = 0.f;
    for (int b = t; b < NBLK_RED; b += 64) {
        float4 p = part4[b];
        ssg += p.x; ssd += p.y; sgd += p.z; mx = fmaxf(mx, p.w);
    }
    #pragma unroll
    for (int off = 32; off > 0; off >>= 1) {
        ssg += __shfl_down(ssg, off);
        ssd += __shfl_down(ssd, off);
        sgd += __shfl_down(sgd, off);
        mx = fmaxf(mx, __shfl_down(mx, off));
    }
    __shared__ float red[4];
    if (t == 0) { red[0] = ssg; red[1] = ssd; red[2] = sgd; red[3] = mx; }
    __syncthreads();

    __shared__ float buf[32];
    __shared__ float nxt[32];
    float gn = sqrtf(red[0]);
    float dn = sqrtf(red[1]);
    float inv_gn = (gn > EPS_F) ? 1.f / gn : 1.f;
    float inv_dn = (dn > EPS_F) ? 1.f / dn : 1.f;
    float it = (float)iter[0];
    if (t < 6) {
        float f = 0.f;
        if (t == 0) f = log1pf(gn);
        else if (t == 1) f = log1pf(dn);
        else if (t == 2) f = red[2] * inv_gn * inv_dn;
        else if (t == 3) f = red[3] * inv_gn;
        else if (t == 4) f = it;
        else f = logf(loss_cur[0]) - logf(loss_old[0]);
        buf[t] = f;
    }
    __syncthreads();
    float acc;
    if (t < 30) {
        acc = lb0[t];
        #pragma unroll
        for (int c = 0; c < 6; ++c) acc = fmaf(lw0[t * 6 + c], buf[c], acc);
        nxt[t] = fmaxf(acc, 0.f);
    }
    __syncthreads();
    if (t < 20) {
        acc = lb1[t];
        #pragma unroll
        for (int c = 0; c < 30; ++c) acc = fmaf(lw1[t * 30 + c], nxt[c], acc);
        buf[t] = fmaxf(acc, 0.f);
    }
    __syncthreads();
    if (t < 10) {
        acc = lb2[t];
        #pragma unroll
        for (int c = 0; c < 20; ++c) acc = fmaf(lw2[t * 20 + c], buf[c], acc);
        nxt[t] = fmaxf(acc, 0.f);
    }
    __syncthreads();
    if (t < 4) {
        acc = lb3[t];
        #pragma unroll
        for (int c = 0; c < 10; ++c) acc = fmaf(lw3[t * 10 + c], nxt[c], acc);
        float s = ((t & 1) == 0) ? acc * inv_gn : acc * inv_dn;  // t=0,2 g-path; t=1,3 d-path
        wsf[WS_SCAL + t] = s;
    }
    if (t == 0) wsf[WS_SCAL + 4] = rsqrtf(1.f + it);
}

// MFMA conv stack: each wave handles 256 elements (8 tiles of 32 columns).
// 32x32x16 chain: 7 MFMAs/tile (hazard-padded asm, persistent opaque zero
// C-block); layer transitions via 2 permlane32_swaps. xs/os are wave-private
// -> no __syncthreads needed (same-wave LDS RAW ordered by lgkmcnt).
__global__ __launch_bounds__(256) void apply_k(const float4* __restrict__ g4,
                                               const float4* __restrict__ a4,
                                               const float4* __restrict__ b4,
                                               const float4* __restrict__ gp4,
                                               const float4* __restrict__ ex4,
                                               const float* __restrict__ wsf,
                                               float4* __restrict__ out4) {
    __shared__ uint2 xs[4][256];                    // per-elem packed x channels (4 f16)
    __shared__ __align__(16) float os[4][256];      // per-elem conv output (f32)

    const int lane = threadIdx.x & 63;
    const int wv   = threadIdx.x >> 6;
    const bool low = lane < 32;

    const float s0 = wsf[WS_SCAL + 0], s1 = wsf[WS_SCAL + 1];
    const float s2 = wsf[WS_SCAL + 2], s3 = wsf[WS_SCAL + 3];
    const float isq = wsf[WS_SCAL + 4];

    // weight A-fragments (pre-packed by mlp_k), 16B/lane coalesced
    const uint4* __restrict__ frg = (const uint4*)(wsf + WS_FRG);
    i32x4 wf[7];
    #pragma unroll
    for (int f = 0; f < 7; ++f) {
        uint4 u = frg[f * 64 + lane];
        wf[f] = (i32x4){(int)u.x, (int)u.y, (int)u.z, (int)u.w};
    }

    const int i4 = blockIdx.x * 256 + threadIdx.x;  // this thread's float4 slot
    float4 gv = g4[i4], av = a4[i4], bv = b4[i4], pv = gp4[i4], ev = ex4[i4];
    float GG[4] = {gv.x, gv.y, gv.z, gv.w};
    float PP[4] = {pv.x, pv.y, pv.z, pv.w};
    float EE[4] = {ev.x, ev.y, ev.z, ev.w};
    float DE[4] = {bv.x - av.x, bv.y - av.y, bv.z - av.z, bv.w - av.w};

    // stage x channels to LDS: 4 f16 per element {x0,x1,x2,x3}
    #pragma unroll
    for (int e = 0; e < 4; ++e) {
        float x0 = s0 * PP[e] * GG[e];
        float x1 = s1 * EE[e] * DE[e];
        float x2 = s2 * GG[e];
        float x3 = s3 * DE[e];
        h2 lo = pkrtz(x0, x1);
        h2 hi = pkrtz(x2, x3);
        xs[wv][(lane << 2) + e] = make_uint2(h2_bits(lo), h2_bits(hi));
    }

    // persistent zero C-block. The opaque asm makes it non-rematerializable:
    // without it, LLVM re-zeroes the tied C/D block before every seeded MFMA
    // (zero is a remat-able constant) = R4's 64 parasitic movs/tile.
    f32x16 Zc;
    #pragma unroll
    for (int k = 0; k < 16; ++k) Zc[k] = 0.f;
    asm volatile("" : "+v"(Zc));

    #pragma unroll
    for (int tl = 0; tl < 8; ++tl) {
        uint2 xv = xs[wv][(tl << 5) + (lane & 31)];
        // L0 B (K=16): words {x01, x23, bias1.0, dc}; hi-lane words hit
        // zero-padded weight columns k8-15 -> content irrelevant.
        i32x4 b0 = (i32x4){(int)xv.x, (int)xv.y, 0x00003C00, 0};
        f32x16 a0 = mfma_pad(wf[0], b0, Zc);

        i32x4 c0, c1;
        transition(a0, c0, c1);
        f32x16 a1 = mfma_chain(wf[1], c0, Zc);
        a1 = mfma_pad(wf[2], c1, a1);

        transition(a1, c0, c1);
        f32x16 a2 = mfma_chain(wf[3], c0, Zc);
        a2 = mfma_pad(wf[4], c1, a2);

        transition(a2, c0, c1);
        f32x16 a3 = mfma_chain(wf[5], c0, Zc);
        a3 = mfma_pad(wf[6], c1, a3);

        // direction for this tile's 32 columns lives in reg0 of lanes 0-31
        if (low) os[wv][(tl << 5) + lane] = a3[0];
    }

    const float4 ov = *reinterpret_cast<const float4*>(&os[wv][lane << 2]);
    float4 outv;
    outv.x = fmaf(ov.x, isq, bv.x);
    outv.y = fmaf(ov.y, isq, bv.y);
    outv.z = fmaf(ov.z, isq, bv.z);
    outv.w = fmaf(ov.w, isq, bv.w);
    out4[i4] = outv;
}

extern "C" void kernel_launch(void* const* d_in, const int* in_sizes, int n_in,
                              void* d_out, int out_size, void* d_ws, size_t ws_size,
                              hipStream_t stream) {
    const float* grad    = (const float*)d_in[0];
    const float* state0  = (const float*)d_in[1];
    const float* state1  = (const float*)d_in[2];
    const float* losscur = (const float*)d_in[3];
    const float* lossold = (const float*)d_in[4];
    const int*   iter    = (const int*)d_in[5];
    const float* gparam  = (const float*)d_in[6];
    const float* extrap  = (const float*)d_in[7];
    const float* cw0 = (const float*)d_in[8];  const float* cb0 = (const float*)d_in[9];
    const float* cw1 = (const float*)d_in[10]; const float* cb1 = (const float*)d_in[11];
    const float* cw2 = (const float*)d_in[12]; const float* cb2 = (const float*)d_in[13];
    const float* cw3 = (const float*)d_in[14]; const float* cb3 = (const float*)d_in[15];
    const float* lw0 = (const float*)d_in[16]; const float* lb0 = (const float*)d_in[17];
    const float* lw1 = (const float*)d_in[18]; const float* lb1 = (const float*)d_in[19];
    const float* lw2 = (const float*)d_in[20]; const float* lb2 = (const float*)d_in[21];
    const float* lw3 = (const float*)d_in[22]; const float* lb3 = (const float*)d_in[23];

    float* wsf = (float*)d_ws;
    float* out = (float*)d_out;

    reduce_k<<<NBLK_RED, 256, 0, stream>>>((const float4*)grad, (const float4*)state0,
                                           (const float4*)state1, (float4*)wsf);

    mlp_k<<<1, 64, 0, stream>>>(wsf, losscur, lossold, iter,
                                lw0, lb0, lw1, lb1, lw2, lb2, lw3, lb3,
                                cw0, cb0, cw1, cb1, cw2, cb2, cw3, cb3);

    apply_k<<<DIM / 1024, 256, 0, stream>>>((const float4*)grad, (const float4*)state0,
                                            (const float4*)state1, (const float4*)gparam,
                                            (const float4*)extrap,
                                            wsf, (float4*)out);
}